// Round 2
// baseline (1220.927 us; speedup 1.0000x reference)
//
#include <hip/hip_runtime.h>

#define NN 262144
#define DD 128
#define KK 512
#define GG 4096
#define TT 10

// output layout (f32, flat, return order)
#define GT       40960ull                 /* G*T */
#define Z_OFF    122880ull                /* 3*GT */
#define PC_OFF   33677312ull              /* Z_OFF + N*D */
#define PX_OFF   34201600ull              /* PC_OFF + G*D */

// ws layout: [0, 2048)  c2 (512 f32);  [4096, 4096+4*N) idx (int32)

__global__ __launch_bounds__(256) void c2_kernel(const float* __restrict__ ccb,
                                                 float* __restrict__ c2) {
    int k = blockIdx.x * blockDim.x + threadIdx.x;
    if (k < KK) {
        float s = 0.f;
        #pragma unroll 8
        for (int j = 0; j < DD; ++j) { float v = ccb[k * DD + j]; s = fmaf(v, v, s); }
        c2[k] = s;
    }
}

// 1 thread = 1 node. x row in registers; codeword loads are wave-uniform
// (k is thread-invariant) -> scalar loads, SGPR operand into v_fmac.
__global__ __launch_bounds__(256) void argmin_kernel(
    const float* __restrict__ x, const float* __restrict__ ccb,
    const float* __restrict__ c2, const float* __restrict__ codebook,
    int* __restrict__ idx_out, float* __restrict__ z_out)
{
    const int node = blockIdx.x * 256 + threadIdx.x;

    float4 xr[32];
    const float4* xrow = (const float4*)(x + (size_t)node * DD);
    float x2 = 0.f;
    #pragma unroll
    for (int j = 0; j < 32; ++j) {
        xr[j] = xrow[j];
        x2 += xr[j].x * xr[j].x + xr[j].y * xr[j].y
            + xr[j].z * xr[j].z + xr[j].w * xr[j].w;
    }

    float best = 3.4e38f;
    int   bi   = 0;
    #pragma unroll 2
    for (int k = 0; k < KK; ++k) {
        const float4* cw = (const float4*)(ccb + (size_t)k * DD); // uniform addr
        float d0 = 0.f, d1 = 0.f, d2 = 0.f, d3 = 0.f;             // 4 indep chains
        #pragma unroll
        for (int j = 0; j < 32; ++j) {
            float4 c = cw[j];
            d0 = fmaf(xr[j].x, c.x, d0);
            d1 = fmaf(xr[j].y, c.y, d1);
            d2 = fmaf(xr[j].z, c.z, d2);
            d3 = fmaf(xr[j].w, c.w, d3);
        }
        // match reference op shape: (x2 + c2) - 2*dot  (tie-rounding parity)
        float s = (x2 + c2[k]) - 2.f * ((d0 + d1) + (d2 + d3));
        if (s < best) { best = s; bi = k; }   // strict < keeps FIRST min (jnp.argmin)
    }
    idx_out[node] = bi;

    const float4* zr = (const float4*)(codebook + (size_t)bi * DD);
    float4*       zo = (float4*)(z_out + (size_t)node * DD);
    #pragma unroll
    for (int j = 0; j < 32; ++j) zo[j] = zr[j];
}

// 1 block = 1 graph (batch is sorted). thread d accumulates dimension d.
// Fuses pooled_x / pooled_causal / pooled_counter and the [T=10] FC heads.
__global__ __launch_bounds__(128) void pool_kernel(
    const float* __restrict__ x, const void* __restrict__ batch,
    const int* __restrict__ idx, const float* __restrict__ ccb,
    const float* __restrict__ cnb, const float* __restrict__ fcw,
    const float* __restrict__ fcb, float* __restrict__ out)
{
    const int g   = blockIdx.x;
    const int tid = threadIdx.x;

    __shared__ int   s_range[2];
    __shared__ float s_pool[3][DD];

    const int* b32 = (const int*)batch;
    // dtype sniff, in-bounds for both int32[N] and int64[N] layouts:
    // word N-1 is the hi word of batch[(N-1)/2] (==0) if int64, else batch[N-1] (~4095).
    const bool mode64 = (b32[NN - 1] == 0);

    if (tid == 0) {
        const long long* b64 = (const long long*)batch;
        int lo, hi;
        // lower_bound(g)
        lo = 0; hi = NN;
        while (lo < hi) {
            int mid = (lo + hi) >> 1;
            int v = mode64 ? (int)b64[mid] : b32[mid];
            if (v < g) lo = mid + 1; else hi = mid;
        }
        s_range[0] = lo;
        // lower_bound(g+1)
        hi = NN;
        while (lo < hi) {
            int mid = (lo + hi) >> 1;
            int v = mode64 ? (int)b64[mid] : b32[mid];
            if (v < g + 1) lo = mid + 1; else hi = mid;
        }
        s_range[1] = lo;
    }
    __syncthreads();

    const int start = s_range[0], end = s_range[1];

    float sx = 0.f, sca = 0.f, sco = 0.f;
    for (int n = start; n < end; ++n) {
        sx += x[(size_t)n * DD + tid];
        int k = idx[n];                        // uniform per block iter
        sca += ccb[(size_t)k * DD + tid];      // coalesced, L2-resident
        sco += cnb[(size_t)k * DD + tid];
    }
    float cnt = (float)(end - start);
    float inv = 1.f / fmaxf(cnt, 1.f);
    float px  = sx * inv;
    float pca = px + sca * inv;
    float pco = sco * inv;

    out[PX_OFF + (size_t)g * DD + tid] = px;
    out[PC_OFF + (size_t)g * DD + tid] = pca;

    s_pool[0][tid] = pca;   // -> causal_pre
    s_pool[1][tid] = pco;   // -> counter_pre
    s_pool[2][tid] = px;    // -> y_pre (detached weights == same values)
    __syncthreads();

    if (tid < 3 * TT) {
        int vec = tid / TT;
        int t   = tid % TT;
        float acc = fcb[t];
        #pragma unroll 8
        for (int j = 0; j < DD; ++j) acc = fmaf(s_pool[vec][j], fcw[t * DD + j], acc);
        out[(size_t)vec * GT + (size_t)g * TT + t] = acc;
    }
}

extern "C" void kernel_launch(void* const* d_in, const int* in_sizes, int n_in,
                              void* d_out, int out_size, void* d_ws, size_t ws_size,
                              hipStream_t stream) {
    const float* x    = (const float*)d_in[0];
    const void*  batch= d_in[1];
    const float* cb   = (const float*)d_in[2];
    const float* ccb  = (const float*)d_in[3];
    const float* cnb  = (const float*)d_in[4];
    const float* fcw  = (const float*)d_in[5];
    const float* fcb  = (const float*)d_in[6];
    float* out = (float*)d_out;

    float* c2  = (float*)d_ws;
    int*   idx = (int*)((char*)d_ws + 4096);

    c2_kernel<<<2, 256, 0, stream>>>(ccb, c2);
    argmin_kernel<<<NN / 256, 256, 0, stream>>>(x, ccb, c2, cb, idx, out + Z_OFF);
    pool_kernel<<<GG, 128, 0, stream>>>(x, batch, idx, ccb, cnb, fcw, fcb, out);
}

// Round 4
// 886.949 us; speedup vs baseline: 1.3765x; 1.3765x over previous
//
#include <hip/hip_runtime.h>

#define NN 262144
#define DD 128
#define KK 512
#define GG 4096
#define TT 10

// output layout (f32, flat, return order)
#define GT       40960ull                 /* G*T */
#define Z_OFF    122880ull                /* 3*GT */
#define PC_OFF   33677312ull              /* Z_OFF + N*D */
#define PX_OFF   34201600ull              /* PC_OFF + G*D */

// ws: [0,2048) c2;  [4096, 4096+4*NN) idx   -- within round-2-proven ws size.
// ct (transposed codebook, 64K floats) borrows d_out+PC_OFF: written first,
// read by argmin, then overwritten by pool_kernel. No extra ws needed.

__global__ __launch_bounds__(256) void ct_kernel(const float* __restrict__ ccb,
                                                 float* __restrict__ ct) {
    int i = blockIdx.x * 256 + threadIdx.x;      // 65536 = 128*512
    int d = i >> 9, k = i & 511;
    ct[i] = ccb[k * DD + d];                     // ct[d][k]
}

__global__ __launch_bounds__(256) void c2_kernel(const float* __restrict__ ccb,
                                                 float* __restrict__ c2) {
    int k = blockIdx.x * blockDim.x + threadIdx.x;
    if (k < KK) {
        float s = 0.f;
        #pragma unroll 8
        for (int j = 0; j < DD; ++j) { float v = ccb[k * DD + j]; s = fmaf(v, v, s); }
        c2[k] = s;
    }
}

// Block = 128 thr = 2 waves over 64 nodes. Wave w owns dims [w*64, w*64+64).
// x half-row in 64 VGPRs; codeword lines are wave-uniform loads from ct[d][k];
// 16-k accumulator tile (2 chains per half); cross-wave combine in LDS;
// argmin via packed (ordered_score, k) u64 atomicMin = exact first-index tie-break.
// Score shape matches the round-2 PASSING kernel: (x2 + c2[k]) - 2*((A+B)+(A'+B')).
__global__ __launch_bounds__(128) void argmin_kernel(
    const float* __restrict__ x, const float* __restrict__ ct,
    const float* __restrict__ c2, const float* __restrict__ codebook,
    int* __restrict__ idx_out, float* __restrict__ z_out)
{
    const int tid  = threadIdx.x;
    const int lane = tid & 63;
    const int w    = __builtin_amdgcn_readfirstlane(tid >> 6);   // dim-half, uniform
    const int node = blockIdx.x * 64 + lane;

    __shared__ float part[16 * 128];
    __shared__ float s_x2[2][64];
    __shared__ unsigned long long best64[64];
    __shared__ int s_bi[64];

    if (tid < 64) best64[tid] = ~0ull;

    float4 xr[16];
    const float4* xp = (const float4*)(x + (size_t)node * DD + w * 64);
    float x2h = 0.f;
    #pragma unroll
    for (int j = 0; j < 16; ++j) {
        xr[j] = xp[j];
        x2h += xr[j].x * xr[j].x + xr[j].y * xr[j].y
             + xr[j].z * xr[j].z + xr[j].w * xr[j].w;
    }
    s_x2[w][lane] = x2h;

    const float* ctw = ct + (size_t)w * 64 * KK;
    __syncthreads();
    const float x2 = s_x2[0][lane] + s_x2[1][lane];   // common across k: can't flip argmin

    for (int grp = 0; grp < 32; ++grp) {
        const int kbase = grp * 16;
        float accA[16], accB[16];
        #pragma unroll
        for (int kk = 0; kk < 16; ++kk) { accA[kk] = 0.f; accB[kk] = 0.f; }

        const float* cp = ctw + kbase;
        #pragma unroll
        for (int d4 = 0; d4 < 16; ++d4) {
            const float4 xv = xr[d4];
            const float* l0 = cp + (size_t)(d4 * 4 + 0) * KK;   // uniform lines
            const float* l1 = cp + (size_t)(d4 * 4 + 1) * KK;
            const float* l2 = cp + (size_t)(d4 * 4 + 2) * KK;
            const float* l3 = cp + (size_t)(d4 * 4 + 3) * KK;
            #pragma unroll
            for (int kk = 0; kk < 16; ++kk) accA[kk] = fmaf(xv.x, l0[kk], accA[kk]);
            #pragma unroll
            for (int kk = 0; kk < 16; ++kk) accA[kk] = fmaf(xv.y, l1[kk], accA[kk]);
            #pragma unroll
            for (int kk = 0; kk < 16; ++kk) accB[kk] = fmaf(xv.z, l2[kk], accB[kk]);
            #pragma unroll
            for (int kk = 0; kk < 16; ++kk) accB[kk] = fmaf(xv.w, l3[kk], accB[kk]);
        }

        #pragma unroll
        for (int kk = 0; kk < 16; ++kk)
            part[kk * 128 + w * 64 + lane] = accA[kk] + accB[kk];   // (A+B) per half
        __syncthreads();

        // this wave scores kk in [w*8, w*8+8)
        unsigned long long lbest = ~0ull;
        #pragma unroll
        for (int j = 0; j < 8; ++j) {
            const int kk = w * 8 + j;
            const float p = part[kk * 128 + lane] + part[kk * 128 + 64 + lane];
            const float s = (x2 + c2[kbase + kk]) - 2.f * p;   // round-2 shape
            unsigned u = __float_as_uint(s);
            u = (u & 0x80000000u) ? ~u : (u | 0x80000000u);    // order-preserving
            unsigned long long key =
                ((unsigned long long)u << 32) | (unsigned)(kbase + kk);
            lbest = (key < lbest) ? key : lbest;
        }
        atomicMin(&best64[lane], lbest);
        __syncthreads();   // also protects part[] before next group's writes
    }

    if (tid < 64) {
        const int bi = (int)(best64[tid] & 511u);
        s_bi[tid] = bi;
        idx_out[node] = bi;
    }
    __syncthreads();

    // z gather: 2 threads per row
    const int r = tid >> 1, half = tid & 1;
    const int bi = s_bi[r];
    const float4* src = (const float4*)(codebook + (size_t)bi * DD + half * 64);
    float4*       dst = (float4*)(z_out + ((size_t)blockIdx.x * 64 + r) * DD + half * 64);
    #pragma unroll
    for (int j = 0; j < 16; ++j) dst[j] = src[j];
}

// 1 block = 1 graph; 2 rows in flight x 128 dims; LDS combine; FC heads.
__global__ __launch_bounds__(256) void pool_kernel(
    const float* __restrict__ x, const void* __restrict__ batch,
    const int* __restrict__ idx, const float* __restrict__ ccb,
    const float* __restrict__ cnb, const float* __restrict__ fcw,
    const float* __restrict__ fcb, float* __restrict__ out)
{
    const int g = blockIdx.x, tid = threadIdx.x;
    const int rid = tid >> 7, d = tid & 127;

    __shared__ int   s_range[2];
    __shared__ float s_red[3][128];
    __shared__ float s_pool[3][128];

    const int* b32 = (const int*)batch;
    const bool mode64 = (b32[NN - 1] == 0);   // int64 vs int32 sniff (in-bounds both ways)

    if (tid == 0) {
        const long long* b64 = (const long long*)batch;
        int lo = 0, hi = NN;
        while (lo < hi) { int mid = (lo + hi) >> 1;
            int v = mode64 ? (int)b64[mid] : b32[mid];
            if (v < g) lo = mid + 1; else hi = mid; }
        s_range[0] = lo;
        hi = NN;
        while (lo < hi) { int mid = (lo + hi) >> 1;
            int v = mode64 ? (int)b64[mid] : b32[mid];
            if (v <= g) lo = mid + 1; else hi = mid; }
        s_range[1] = lo;
    }
    __syncthreads();
    const int start = s_range[0], end = s_range[1];

    float sx = 0.f, sca = 0.f, sco = 0.f;
    for (int n = start + rid; n < end; n += 2) {
        sx += x[(size_t)n * DD + d];
        int k = idx[n];
        sca += ccb[(size_t)k * DD + d];
        sco += cnb[(size_t)k * DD + d];
    }
    if (rid == 1) { s_red[0][d] = sx; s_red[1][d] = sca; s_red[2][d] = sco; }
    __syncthreads();
    if (rid == 0) {
        sx += s_red[0][d]; sca += s_red[1][d]; sco += s_red[2][d];
        float cnt = (float)(end - start);
        float inv = 1.f / fmaxf(cnt, 1.f);
        float px  = sx * inv;
        float pca = px + sca * inv;
        float pco = sco * inv;
        out[PX_OFF + (size_t)g * DD + d] = px;
        out[PC_OFF + (size_t)g * DD + d] = pca;
        s_pool[0][d] = pca; s_pool[1][d] = pco; s_pool[2][d] = px;
    }
    __syncthreads();
    if (tid < 3 * TT) {
        int vec = tid / TT, t = tid % TT;
        float a = fcb[t];
        #pragma unroll 8
        for (int j = 0; j < DD; ++j) a = fmaf(s_pool[vec][j], fcw[t * DD + j], a);
        out[(size_t)vec * GT + (size_t)g * TT + t] = a;
    }
}

extern "C" void kernel_launch(void* const* d_in, const int* in_sizes, int n_in,
                              void* d_out, int out_size, void* d_ws, size_t ws_size,
                              hipStream_t stream) {
    const float* x    = (const float*)d_in[0];
    const void*  batch= d_in[1];
    const float* cb   = (const float*)d_in[2];
    const float* ccb  = (const float*)d_in[3];
    const float* cnb  = (const float*)d_in[4];
    const float* fcw  = (const float*)d_in[5];
    const float* fcb  = (const float*)d_in[6];
    float* out = (float*)d_out;

    float* c2  = (float*)d_ws;
    int*   idx = (int*)((char*)d_ws + 4096);
    float* ct  = out + PC_OFF;               // borrowed, overwritten by pool_kernel

    ct_kernel<<<256, 256, 0, stream>>>(ccb, ct);
    c2_kernel<<<2, 256, 0, stream>>>(ccb, c2);
    argmin_kernel<<<NN / 64, 128, 0, stream>>>(x, ct, c2, cb, idx, out + Z_OFF);
    pool_kernel<<<GG, 256, 0, stream>>>(x, batch, idx, ccb, cnb, fcw, fcb, out);
}

// Round 5
// 499.680 us; speedup vs baseline: 2.4434x; 1.7750x over previous
//
#include <hip/hip_runtime.h>

#define NN 262144
#define DD 128
#define KK 512
#define GG 4096
#define TT 10

// output layout (f32, flat, return order)
#define GT       40960ull                 /* G*T */
#define Z_OFF    122880ull                /* 3*GT */
#define PC_OFF   33677312ull              /* Z_OFF + N*D */
#define PX_OFF   34201600ull              /* PC_OFF + G*D */

#define MARGIN   2.0e-2f   /* > 2x worst-case approx score error (~7e-3) */

// ws: [0,2048) c2;  [4096, 4096+4*NN) idx  -- round-4-proven footprint.
// bpack (256KB bf16 B-frags) + flag cnt/list borrow out+PC_OFF (2MB region),
// consumed before pool_kernel overwrites it.

typedef __attribute__((ext_vector_type(8))) short bf16x8;
typedef __attribute__((ext_vector_type(4))) float f32x4;

static __device__ __forceinline__ unsigned short f2bf(float f) {
    unsigned u = __float_as_uint(f);
    return (unsigned short)((u + 0x7FFFu + ((u >> 16) & 1u)) >> 16);   // RN-even
}
static __device__ __forceinline__ float bf2f(unsigned short h) {
    return __uint_as_float(((unsigned)h) << 16);
}

// 512 waves: one code per wave. Also zeroes the flag counter.
__global__ __launch_bounds__(256) void prep_c2_kernel(const float* __restrict__ ccb,
                                                      float* __restrict__ c2,
                                                      int* __restrict__ flag_cnt) {
    if (blockIdx.x == 0 && threadIdx.x == 0) *flag_cnt = 0;
    const int wid  = (blockIdx.x * 256 + threadIdx.x) >> 6;   // 0..511
    const int lane = threadIdx.x & 63;
    const float* cr = ccb + (size_t)wid * DD;
    float a = cr[2 * lane], b = cr[2 * lane + 1];
    float s = a * a + b * b;
    #pragma unroll
    for (int off = 1; off < 64; off <<= 1) s += __shfl_xor(s, off, 64);
    if (lane == 0) c2[wid] = s;
}

// B-frag pack: bp[((ct*8+s4)*64+lane)*8+j]; s4<4 -> ch of dims (s4)*32+(lane>>4)*8+j,
// s4>=4 -> cl of dims (s4-4)*32+...; code = ct*16+(lane&15).
// Slot->dim map matches the A-side packing exactly (k-permutation cancels).
__global__ __launch_bounds__(256) void prep_bpack_kernel(const float* __restrict__ ccb,
                                                         unsigned short* __restrict__ bp) {
    const int i    = blockIdx.x * 256 + threadIdx.x;   // 16384 threads
    const int lane = i & 63;
    const int s4   = (i >> 6) & 7;
    const int ct   = i >> 9;
    const int code = ct * 16 + (lane & 15);
    const int dim0 = (s4 & 3) * 32 + (lane >> 4) * 8;
    const float* src = ccb + (size_t)code * DD + dim0;
    unsigned short* dst = bp + (size_t)i * 8;
    const bool lo = (s4 >= 4);
    #pragma unroll
    for (int j = 0; j < 8; ++j) {
        float v = src[j];
        unsigned short h = f2bf(v);
        dst[j] = lo ? f2bf(v - bf2f(h)) : h;
    }
}

// Block = 256 thr = 4 waves; wave handles 32 nodes (2 MFMA row-tiles).
// dot via 16 bf16 MFMAs per (ctile, node-tile): (xh+xl)x(ch+cl) all 4 terms.
// Running (best, second-best) per node; gap < MARGIN -> flag for exact rescore.
__global__ __launch_bounds__(256) void argmin_mfma_kernel(
    const float* __restrict__ x, const unsigned short* __restrict__ bp,
    const float* __restrict__ c2, const float* __restrict__ codebook,
    int* __restrict__ idx_out, float* __restrict__ z_out,
    int* __restrict__ flag_cnt, int* __restrict__ flag_list)
{
    const int tid  = threadIdx.x;
    const int lane = tid & 63;
    const int wv   = tid >> 6;
    const int nodebase = blockIdx.x * 128 + wv * 32;
    const int col = lane & 15;
    const int hi  = lane >> 4;

    __shared__ int s_idx[128];

    // A-frags: row = nodebase + t*16 + col; slot (kk,j) -> dim kk*32 + hi*8 + j
    bf16x8 ah[2][4], al[2][4];
    #pragma unroll
    for (int t = 0; t < 2; ++t) {
        const float* xr = x + (size_t)(nodebase + t * 16 + col) * DD + hi * 8;
        #pragma unroll
        for (int kk = 0; kk < 4; ++kk) {
            float4 u0 = *(const float4*)(xr + kk * 32);
            float4 u1 = *(const float4*)(xr + kk * 32 + 4);
            float f[8] = {u0.x, u0.y, u0.z, u0.w, u1.x, u1.y, u1.z, u1.w};
            bf16x8 H, L;
            #pragma unroll
            for (int j = 0; j < 8; ++j) {
                unsigned short h = f2bf(f[j]);
                H[j] = (short)h;
                L[j] = (short)f2bf(f[j] - bf2f(h));
            }
            ah[t][kk] = H; al[t][kk] = L;
        }
    }

    float b1s[2][4], b2s[2][4]; int b1i[2][4];
    #pragma unroll
    for (int t = 0; t < 2; ++t)
        #pragma unroll
        for (int r = 0; r < 4; ++r) { b1s[t][r] = 3.4e38f; b2s[t][r] = 3.4e38f; b1i[t][r] = 0; }

    const bf16x8* bpf = (const bf16x8*)bp;

    for (int ct = 0; ct < 32; ++ct) {
        bf16x8 bh[4], bl[4];
        #pragma unroll
        for (int kk = 0; kk < 4; ++kk) {
            bh[kk] = bpf[(ct * 8 + kk) * 64 + lane];
            bl[kk] = bpf[(ct * 8 + 4 + kk) * 64 + lane];
        }
        f32x4 acc0 = {0.f, 0.f, 0.f, 0.f}, acc1 = {0.f, 0.f, 0.f, 0.f};
        #pragma unroll
        for (int kk = 0; kk < 4; ++kk) {
            acc0 = __builtin_amdgcn_mfma_f32_16x16x32_bf16(ah[0][kk], bh[kk], acc0, 0, 0, 0);
            acc1 = __builtin_amdgcn_mfma_f32_16x16x32_bf16(ah[1][kk], bh[kk], acc1, 0, 0, 0);
        }
        #pragma unroll
        for (int kk = 0; kk < 4; ++kk) {
            acc0 = __builtin_amdgcn_mfma_f32_16x16x32_bf16(ah[0][kk], bl[kk], acc0, 0, 0, 0);
            acc1 = __builtin_amdgcn_mfma_f32_16x16x32_bf16(ah[1][kk], bl[kk], acc1, 0, 0, 0);
        }
        #pragma unroll
        for (int kk = 0; kk < 4; ++kk) {
            acc0 = __builtin_amdgcn_mfma_f32_16x16x32_bf16(al[0][kk], bh[kk], acc0, 0, 0, 0);
            acc1 = __builtin_amdgcn_mfma_f32_16x16x32_bf16(al[1][kk], bh[kk], acc1, 0, 0, 0);
        }
        #pragma unroll
        for (int kk = 0; kk < 4; ++kk) {
            acc0 = __builtin_amdgcn_mfma_f32_16x16x32_bf16(al[0][kk], bl[kk], acc0, 0, 0, 0);
            acc1 = __builtin_amdgcn_mfma_f32_16x16x32_bf16(al[1][kk], bl[kk], acc1, 0, 0, 0);
        }
        const float c2v  = c2[ct * 16 + col];
        const int   code = ct * 16 + col;
        #pragma unroll
        for (int r = 0; r < 4; ++r) {
            {   float s = fmaf(-2.f, acc0[r], c2v);            // x2 const/node: drops
                bool lt = s < b1s[0][r];
                float old1 = b1s[0][r];
                float cand2 = lt ? old1 : s;                   // ==best -> gap 0 -> flag
                b1s[0][r] = lt ? s : old1;
                b1i[0][r] = lt ? code : b1i[0][r];
                b2s[0][r] = fminf(b2s[0][r], cand2); }
            {   float s = fmaf(-2.f, acc1[r], c2v);
                bool lt = s < b1s[1][r];
                float old1 = b1s[1][r];
                float cand2 = lt ? old1 : s;
                b1s[1][r] = lt ? s : old1;
                b1i[1][r] = lt ? code : b1i[1][r];
                b2s[1][r] = fminf(b2s[1][r], cand2); }
        }
    }

    // reduce (best1, best2) across the 16 cols of each row-group (first-idx ties)
    #pragma unroll
    for (int off = 1; off < 16; off <<= 1) {
        #pragma unroll
        for (int t = 0; t < 2; ++t)
            #pragma unroll
            for (int r = 0; r < 4; ++r) {
                float o1s = __shfl_xor(b1s[t][r], off, 64);
                int   o1i = __shfl_xor(b1i[t][r], off, 64);
                float o2s = __shfl_xor(b2s[t][r], off, 64);
                bool owin = (o1s < b1s[t][r]) || (o1s == b1s[t][r] && o1i < b1i[t][r]);
                float loser = owin ? b1s[t][r] : o1s;
                b2s[t][r] = fminf(fminf(b2s[t][r], o2s), loser);
                b1s[t][r] = owin ? o1s : b1s[t][r];
                b1i[t][r] = owin ? o1i : b1i[t][r];
            }
    }

    if (col == 0) {
        #pragma unroll
        for (int t = 0; t < 2; ++t)
            #pragma unroll
            for (int r = 0; r < 4; ++r) {
                const int node = nodebase + t * 16 + hi * 4 + r;   // C row mapping (m89)
                const int bi = b1i[t][r];
                idx_out[node] = bi;
                s_idx[wv * 32 + t * 16 + hi * 4 + r] = bi;
                if (b2s[t][r] - b1s[t][r] < MARGIN) {
                    int p = atomicAdd(flag_cnt, 1);
                    flag_list[p] = node;
                }
            }
    }
    __syncthreads();

    // z-gather: 8 lanes/row, coalesced 128B chunks
    const int rsub = lane >> 3, csub = lane & 7;
    for (int it = 0; it < 4; ++it) {
        const int lrow = it * 8 + rsub;
        const int bi = s_idx[wv * 32 + lrow];
        const float4* src = (const float4*)(codebook + (size_t)bi * DD) + csub;
        float4* dst = (float4*)(z_out + (size_t)(nodebase + lrow) * DD) + csub;
        #pragma unroll
        for (int j = 0; j < 4; ++j) dst[j * 8] = src[j * 8];
    }
}

// one wave per flagged node: exact f32 512-code rescore, first-index tie-break.
__global__ __launch_bounds__(256) void rescore_kernel(
    const float* __restrict__ x, const float* __restrict__ ccb,
    const float* __restrict__ c2, const float* __restrict__ codebook,
    const int* __restrict__ flag_cnt, const int* __restrict__ flag_list,
    int* __restrict__ idx_out, float* __restrict__ z_out)
{
    const int lane = threadIdx.x & 63;
    const int wid  = (blockIdx.x * 256 + threadIdx.x) >> 6;
    const int nw   = gridDim.x * 4;
    const int total = *flag_cnt;
    for (int i = wid; i < total; i += nw) {
        const int node = flag_list[i];
        const float4* x4 = (const float4*)(x + (size_t)node * DD);
        float x2 = 0.f;
        float4 xv[32];
        #pragma unroll
        for (int j = 0; j < 32; ++j) {
            xv[j] = x4[j];
            x2 += xv[j].x * xv[j].x + xv[j].y * xv[j].y
                + xv[j].z * xv[j].z + xv[j].w * xv[j].w;
        }
        unsigned long long best = ~0ull;
        #pragma unroll 2
        for (int c8 = 0; c8 < 8; ++c8) {
            const int k = c8 * 64 + lane;
            const float4* cr = (const float4*)(ccb + (size_t)k * DD);
            float d0 = 0.f, d1 = 0.f, d2 = 0.f, d3 = 0.f;
            #pragma unroll
            for (int j = 0; j < 32; ++j) {
                float4 c = cr[j];
                d0 = fmaf(xv[j].x, c.x, d0);
                d1 = fmaf(xv[j].y, c.y, d1);
                d2 = fmaf(xv[j].z, c.z, d2);
                d3 = fmaf(xv[j].w, c.w, d3);
            }
            float s = (x2 + c2[k]) - 2.f * ((d0 + d1) + (d2 + d3));
            unsigned u = __float_as_uint(s);
            u = (u & 0x80000000u) ? ~u : (u | 0x80000000u);
            unsigned long long key = ((unsigned long long)u << 32) | (unsigned)k;
            best = key < best ? key : best;
        }
        #pragma unroll
        for (int off = 1; off < 64; off <<= 1) {
            unsigned long long o = __shfl_xor(best, off, 64);
            best = o < best ? o : best;
        }
        const int bi = (int)(best & 511u);
        if (lane == 0) idx_out[node] = bi;
        const float* src = codebook + (size_t)bi * DD;
        float2 v; v.x = src[2 * lane]; v.y = src[2 * lane + 1];
        ((float2*)(z_out + (size_t)node * DD))[lane] = v;
    }
}

// 1 block = 1 graph; 4 row-streams x 128 dims; LDS combine; FC heads.
__global__ __launch_bounds__(512) void pool_kernel(
    const float* __restrict__ x, const void* __restrict__ batch,
    const int* __restrict__ idx, const float* __restrict__ ccb,
    const float* __restrict__ cnb, const float* __restrict__ fcw,
    const float* __restrict__ fcb, float* __restrict__ out)
{
    const int g = blockIdx.x, tid = threadIdx.x;
    const int rid = tid >> 7, d = tid & 127;

    __shared__ int   s_range[2];
    __shared__ float s_red[3][3][128];
    __shared__ float s_pool[3][128];

    const int* b32 = (const int*)batch;
    const bool mode64 = (b32[NN - 1] == 0);   // int64 vs int32 sniff

    if (tid == 0) {
        const long long* b64 = (const long long*)batch;
        int lo = 0, hi = NN;
        while (lo < hi) { int mid = (lo + hi) >> 1;
            int v = mode64 ? (int)b64[mid] : b32[mid];
            if (v < g) lo = mid + 1; else hi = mid; }
        s_range[0] = lo;
        hi = NN;
        while (lo < hi) { int mid = (lo + hi) >> 1;
            int v = mode64 ? (int)b64[mid] : b32[mid];
            if (v <= g) lo = mid + 1; else hi = mid; }
        s_range[1] = lo;
    }
    __syncthreads();
    const int start = s_range[0], end = s_range[1];

    float sx = 0.f, sca = 0.f, sco = 0.f;
    for (int n = start + rid; n < end; n += 4) {
        sx += x[(size_t)n * DD + d];
        int k = idx[n];
        sca += ccb[(size_t)k * DD + d];
        sco += cnb[(size_t)k * DD + d];
    }
    if (rid > 0) { s_red[rid - 1][0][d] = sx; s_red[rid - 1][1][d] = sca; s_red[rid - 1][2][d] = sco; }
    __syncthreads();
    if (rid == 0) {
        #pragma unroll
        for (int q = 0; q < 3; ++q) { sx += s_red[q][0][d]; sca += s_red[q][1][d]; sco += s_red[q][2][d]; }
        float cnt = (float)(end - start);
        float inv = 1.f / fmaxf(cnt, 1.f);
        float px  = sx * inv;
        float pca = px + sca * inv;
        float pco = sco * inv;
        out[PX_OFF + (size_t)g * DD + d] = px;
        out[PC_OFF + (size_t)g * DD + d] = pca;
        s_pool[0][d] = pca; s_pool[1][d] = pco; s_pool[2][d] = px;
    }
    __syncthreads();
    if (tid < 3 * TT) {
        int vec = tid / TT, t = tid % TT;
        float a = fcb[t];
        #pragma unroll 8
        for (int j = 0; j < DD; ++j) a = fmaf(s_pool[vec][j], fcw[t * DD + j], a);
        out[(size_t)vec * GT + (size_t)g * TT + t] = a;
    }
}

extern "C" void kernel_launch(void* const* d_in, const int* in_sizes, int n_in,
                              void* d_out, int out_size, void* d_ws, size_t ws_size,
                              hipStream_t stream) {
    const float* x    = (const float*)d_in[0];
    const void*  batch= d_in[1];
    const float* cb   = (const float*)d_in[2];
    const float* ccb  = (const float*)d_in[3];
    const float* cnb  = (const float*)d_in[4];
    const float* fcw  = (const float*)d_in[5];
    const float* fcb  = (const float*)d_in[6];
    float* out = (float*)d_out;

    float* c2  = (float*)d_ws;
    int*   idx = (int*)((char*)d_ws + 4096);
    unsigned short* bpack = (unsigned short*)(out + PC_OFF);       // 256 KB borrow
    int* flag_cnt  = (int*)(out + PC_OFF + 65536);
    int* flag_list = (int*)(out + PC_OFF + 65537);                 // cap ~458K > NN

    prep_c2_kernel  <<<128,  256, 0, stream>>>(ccb, c2, flag_cnt);
    prep_bpack_kernel<<<64,  256, 0, stream>>>(ccb, bpack);
    argmin_mfma_kernel<<<2048, 256, 0, stream>>>(x, bpack, c2, cb, idx, out + Z_OFF,
                                                 flag_cnt, flag_list);
    rescore_kernel  <<<128,  256, 0, stream>>>(x, ccb, c2, cb, flag_cnt, flag_list,
                                               idx, out + Z_OFF);
    pool_kernel     <<<GG,   512, 0, stream>>>(x, batch, idx, ccb, cnb, fcw, fcb, out);
}

// Round 6
// 482.620 us; speedup vs baseline: 2.5298x; 1.0353x over previous
//
#include <hip/hip_runtime.h>

#define NN 262144
#define DD 128
#define KK 512
#define GG 4096
#define TT 10

// output layout (f32, flat, return order)
#define GT       40960ull                 /* G*T */
#define Z_OFF    122880ull                /* 3*GT */
#define PC_OFF   33677312ull              /* Z_OFF + N*D */
#define PX_OFF   34201600ull              /* PC_OFF + G*D */

#define MARGIN   2.0e-2f   /* >> worst-case 3-term approx score error (~7.5e-3) */

// ws: [0,2048) c2;  [4096, 4096+4*NN) idx.
// bpack (256KB) + flag cnt/list borrow out+PC_OFF (2MB), consumed pre-pool.

typedef __attribute__((ext_vector_type(8))) short bf16x8;
typedef __attribute__((ext_vector_type(4))) float f32x4;

static __device__ __forceinline__ unsigned short f2bf(float f) {
    unsigned u = __float_as_uint(f);
    return (unsigned short)((u + 0x7FFFu + ((u >> 16) & 1u)) >> 16);   // RN-even
}
static __device__ __forceinline__ float bf2f(unsigned short h) {
    return __uint_as_float(((unsigned)h) << 16);
}

__global__ __launch_bounds__(256) void prep_c2_kernel(const float* __restrict__ ccb,
                                                      float* __restrict__ c2,
                                                      int* __restrict__ flag_cnt) {
    if (blockIdx.x == 0 && threadIdx.x == 0) *flag_cnt = 0;
    const int wid  = (blockIdx.x * 256 + threadIdx.x) >> 6;   // 0..511
    const int lane = threadIdx.x & 63;
    const float* cr = ccb + (size_t)wid * DD;
    float a = cr[2 * lane], b = cr[2 * lane + 1];
    float s = a * a + b * b;
    #pragma unroll
    for (int off = 1; off < 64; off <<= 1) s += __shfl_xor(s, off, 64);
    if (lane == 0) c2[wid] = s;
}

// bp[((ct*8+s4)*64+lane)*8+j]; s4<4 -> ch, s4>=4 -> cl; dims (s4&3)*32+(lane>>4)*8+j;
// code = ct*16+(lane&15). Per-ct tile = 4096 shorts (8KB), contiguous.
__global__ __launch_bounds__(256) void prep_bpack_kernel(const float* __restrict__ ccb,
                                                         unsigned short* __restrict__ bp) {
    const int i    = blockIdx.x * 256 + threadIdx.x;   // 16384 threads
    const int lane = i & 63;
    const int s4   = (i >> 6) & 7;
    const int ct   = i >> 9;
    const int code = ct * 16 + (lane & 15);
    const int dim0 = (s4 & 3) * 32 + (lane >> 4) * 8;
    const float* src = ccb + (size_t)code * DD + dim0;
    unsigned short* dst = bp + (size_t)i * 8;
    const bool lo = (s4 >= 4);
    #pragma unroll
    for (int j = 0; j < 8; ++j) {
        float v = src[j];
        unsigned short h = f2bf(v);
        dst[j] = lo ? f2bf(v - bf2f(h)) : h;
    }
}

// Block = 256 thr = 4 waves; wave owns 32 nodes (2 row-tiles).
// 3-term bf16 split (xh*ch + xh*cl + xl*ch); xl*cl dropped (<=4e-4, << MARGIN).
// B-tile (8KB/ct) double-buffered in LDS: global->reg early, compute, ds_write late.
__global__ __launch_bounds__(256) void argmin_mfma_kernel(
    const float* __restrict__ x, const unsigned short* __restrict__ bp,
    const float* __restrict__ c2, const float* __restrict__ codebook,
    int* __restrict__ idx_out, float* __restrict__ z_out,
    int* __restrict__ flag_cnt, int* __restrict__ flag_list)
{
    const int tid  = threadIdx.x;
    const int lane = tid & 63;
    const int wv   = tid >> 6;
    const int nodebase = blockIdx.x * 128 + wv * 32;
    const int col = lane & 15;
    const int hi  = lane >> 4;

    __shared__ __align__(16) unsigned short sB[2][4096];   // 2 x 8KB
    __shared__ int s_idx[128];

    // A-frags: row = nodebase + t*16 + col; slot (kk,j) -> dim kk*32 + hi*8 + j
    bf16x8 ah[2][4], al[2][4];
    #pragma unroll
    for (int t = 0; t < 2; ++t) {
        const float* xr = x + (size_t)(nodebase + t * 16 + col) * DD + hi * 8;
        #pragma unroll
        for (int kk = 0; kk < 4; ++kk) {
            float4 u0 = *(const float4*)(xr + kk * 32);
            float4 u1 = *(const float4*)(xr + kk * 32 + 4);
            float f[8] = {u0.x, u0.y, u0.z, u0.w, u1.x, u1.y, u1.z, u1.w};
            bf16x8 H, L;
            #pragma unroll
            for (int j = 0; j < 8; ++j) {
                unsigned short h = f2bf(f[j]);
                H[j] = (short)h;
                L[j] = (short)f2bf(f[j] - bf2f(h));
            }
            ah[t][kk] = H; al[t][kk] = L;
        }
    }

    float b1s[2][4], b2s[2][4]; int b1i[2][4];
    #pragma unroll
    for (int t = 0; t < 2; ++t)
        #pragma unroll
        for (int r = 0; r < 4; ++r) { b1s[t][r] = 3.4e38f; b2s[t][r] = 3.4e38f; b1i[t][r] = 0; }

    // prologue: stage ct=0 tile
    {
        const float4* g4 = (const float4*)bp;
        float4 r0 = g4[tid], r1 = g4[256 + tid];
        float4* l4 = (float4*)sB[0];
        l4[tid] = r0; l4[256 + tid] = r1;
    }
    __syncthreads();

    int cur = 0;
    for (int ct = 0; ct < 32; ++ct) {
        float4 r0, r1;
        if (ct < 31) {                       // issue next-tile loads EARLY
            const float4* g4 = (const float4*)(bp + (size_t)(ct + 1) * 4096);
            r0 = g4[tid]; r1 = g4[256 + tid];
        }

        const bf16x8* Bv = (const bf16x8*)sB[cur];
        bf16x8 bh[4], bl[4];
        #pragma unroll
        for (int kk = 0; kk < 4; ++kk) {
            bh[kk] = Bv[kk * 64 + lane];
            bl[kk] = Bv[(4 + kk) * 64 + lane];
        }

        f32x4 aHH0 = {0.f,0.f,0.f,0.f}, aHH1 = aHH0;
        f32x4 aHL0 = aHH0, aHL1 = aHH0, aLH0 = aHH0, aLH1 = aHH0;
        #pragma unroll
        for (int kk = 0; kk < 4; ++kk) {   // 6 independent chains
            aHH0 = __builtin_amdgcn_mfma_f32_16x16x32_bf16(ah[0][kk], bh[kk], aHH0, 0, 0, 0);
            aHH1 = __builtin_amdgcn_mfma_f32_16x16x32_bf16(ah[1][kk], bh[kk], aHH1, 0, 0, 0);
            aHL0 = __builtin_amdgcn_mfma_f32_16x16x32_bf16(ah[0][kk], bl[kk], aHL0, 0, 0, 0);
            aHL1 = __builtin_amdgcn_mfma_f32_16x16x32_bf16(ah[1][kk], bl[kk], aHL1, 0, 0, 0);
            aLH0 = __builtin_amdgcn_mfma_f32_16x16x32_bf16(al[0][kk], bh[kk], aLH0, 0, 0, 0);
            aLH1 = __builtin_amdgcn_mfma_f32_16x16x32_bf16(al[1][kk], bh[kk], aLH1, 0, 0, 0);
        }

        const float c2v  = c2[ct * 16 + col];
        const int   code = ct * 16 + col;
        #pragma unroll
        for (int r = 0; r < 4; ++r) {
            {   float s = fmaf(-2.f, aLH0[r], c2v);
                s = fmaf(-2.f, aHL0[r], s);
                s = fmaf(-2.f, aHH0[r], s);
                bool lt = s < b1s[0][r];
                float old1 = b1s[0][r];
                float cand2 = lt ? old1 : s;
                b1s[0][r] = lt ? s : old1;
                b1i[0][r] = lt ? code : b1i[0][r];
                b2s[0][r] = fminf(b2s[0][r], cand2); }
            {   float s = fmaf(-2.f, aLH1[r], c2v);
                s = fmaf(-2.f, aHL1[r], s);
                s = fmaf(-2.f, aHH1[r], s);
                bool lt = s < b1s[1][r];
                float old1 = b1s[1][r];
                float cand2 = lt ? old1 : s;
                b1s[1][r] = lt ? s : old1;
                b1i[1][r] = lt ? code : b1i[1][r];
                b2s[1][r] = fminf(b2s[1][r], cand2); }
        }

        if (ct < 31) {                       // write next tile LATE (latency hidden)
            float4* l4 = (float4*)sB[cur ^ 1];
            l4[tid] = r0; l4[256 + tid] = r1;
        }
        __syncthreads();
        cur ^= 1;
    }

    // reduce (best1, best2) across the 16 cols of each row-group (first-idx ties)
    #pragma unroll
    for (int off = 1; off < 16; off <<= 1) {
        #pragma unroll
        for (int t = 0; t < 2; ++t)
            #pragma unroll
            for (int r = 0; r < 4; ++r) {
                float o1s = __shfl_xor(b1s[t][r], off, 64);
                int   o1i = __shfl_xor(b1i[t][r], off, 64);
                float o2s = __shfl_xor(b2s[t][r], off, 64);
                bool owin = (o1s < b1s[t][r]) || (o1s == b1s[t][r] && o1i < b1i[t][r]);
                float loser = owin ? b1s[t][r] : o1s;
                b2s[t][r] = fminf(fminf(b2s[t][r], o2s), loser);
                b1s[t][r] = owin ? o1s : b1s[t][r];
                b1i[t][r] = owin ? o1i : b1i[t][r];
            }
    }

    if (col == 0) {
        #pragma unroll
        for (int t = 0; t < 2; ++t)
            #pragma unroll
            for (int r = 0; r < 4; ++r) {
                const int node = nodebase + t * 16 + hi * 4 + r;   // C row mapping (m89)
                const int bi = b1i[t][r];
                idx_out[node] = bi;
                s_idx[wv * 32 + t * 16 + hi * 4 + r] = bi;
                if (b2s[t][r] - b1s[t][r] < MARGIN) {
                    int p = atomicAdd(flag_cnt, 1);
                    flag_list[p] = node;
                }
            }
    }
    __syncthreads();

    // z-gather: 8 lanes/row, coalesced 128B chunks
    const int rsub = lane >> 3, csub = lane & 7;
    for (int it = 0; it < 4; ++it) {
        const int lrow = it * 8 + rsub;
        const int bi = s_idx[wv * 32 + lrow];
        const float4* src = (const float4*)(codebook + (size_t)bi * DD) + csub;
        float4* dst = (float4*)(z_out + (size_t)(nodebase + lrow) * DD) + csub;
        #pragma unroll
        for (int j = 0; j < 4; ++j) dst[j * 8] = src[j * 8];
    }
}

// one wave per flagged node: exact f32 512-code rescore, first-index tie-break.
__global__ __launch_bounds__(256) void rescore_kernel(
    const float* __restrict__ x, const float* __restrict__ ccb,
    const float* __restrict__ c2, const float* __restrict__ codebook,
    const int* __restrict__ flag_cnt, const int* __restrict__ flag_list,
    int* __restrict__ idx_out, float* __restrict__ z_out)
{
    const int lane = threadIdx.x & 63;
    const int wid  = (blockIdx.x * 256 + threadIdx.x) >> 6;
    const int nw   = gridDim.x * 4;
    const int total = *flag_cnt;
    for (int i = wid; i < total; i += nw) {
        const int node = flag_list[i];
        const float4* x4 = (const float4*)(x + (size_t)node * DD);
        float x2 = 0.f;
        float4 xv[32];
        #pragma unroll
        for (int j = 0; j < 32; ++j) {
            xv[j] = x4[j];
            x2 += xv[j].x * xv[j].x + xv[j].y * xv[j].y
                + xv[j].z * xv[j].z + xv[j].w * xv[j].w;
        }
        unsigned long long best = ~0ull;
        #pragma unroll 2
        for (int c8 = 0; c8 < 8; ++c8) {
            const int k = c8 * 64 + lane;
            const float4* cr = (const float4*)(ccb + (size_t)k * DD);
            float d0 = 0.f, d1 = 0.f, d2 = 0.f, d3 = 0.f;
            #pragma unroll
            for (int j = 0; j < 32; ++j) {
                float4 c = cr[j];
                d0 = fmaf(xv[j].x, c.x, d0);
                d1 = fmaf(xv[j].y, c.y, d1);
                d2 = fmaf(xv[j].z, c.z, d2);
                d3 = fmaf(xv[j].w, c.w, d3);
            }
            float s = (x2 + c2[k]) - 2.f * ((d0 + d1) + (d2 + d3));
            unsigned u = __float_as_uint(s);
            u = (u & 0x80000000u) ? ~u : (u | 0x80000000u);
            unsigned long long key = ((unsigned long long)u << 32) | (unsigned)k;
            best = key < best ? key : best;
        }
        #pragma unroll
        for (int off = 1; off < 64; off <<= 1) {
            unsigned long long o = __shfl_xor(best, off, 64);
            best = o < best ? o : best;
        }
        const int bi = (int)(best & 511u);
        if (lane == 0) idx_out[node] = bi;
        const float* src = codebook + (size_t)bi * DD;
        float2 v; v.x = src[2 * lane]; v.y = src[2 * lane + 1];
        ((float2*)(z_out + (size_t)node * DD))[lane] = v;
    }
}

// 1 block = 1 graph; thread = dims [4q,4q+4) of row-stream rid (8 streams, float4).
__global__ __launch_bounds__(256) void pool_kernel(
    const float* __restrict__ x, const void* __restrict__ batch,
    const int* __restrict__ idx, const float* __restrict__ ccb,
    const float* __restrict__ cnb, const float* __restrict__ fcw,
    const float* __restrict__ fcb, float* __restrict__ out)
{
    const int g = blockIdx.x, tid = threadIdx.x;
    const int q = tid & 31, rid = tid >> 5;

    __shared__ int s_range[2];
    __shared__ float4 s_red[7][3][32];
    __shared__ float4 s_pool4[3][32];

    const int* b32 = (const int*)batch;
    const bool mode64 = (b32[NN - 1] == 0);   // int64 vs int32 sniff

    if (tid == 0) {
        const long long* b64 = (const long long*)batch;
        int lo = 0, hi = NN;
        while (lo < hi) { int mid = (lo + hi) >> 1;
            int v = mode64 ? (int)b64[mid] : b32[mid];
            if (v < g) lo = mid + 1; else hi = mid; }
        s_range[0] = lo;
        hi = NN;
        while (lo < hi) { int mid = (lo + hi) >> 1;
            int v = mode64 ? (int)b64[mid] : b32[mid];
            if (v <= g) lo = mid + 1; else hi = mid; }
        s_range[1] = lo;
    }
    __syncthreads();
    const int start = s_range[0], end = s_range[1];

    float4 sx = {0.f,0.f,0.f,0.f}, sca = sx, sco = sx;
    for (int n = start + rid; n < end; n += 8) {
        const float4 xv = *(const float4*)(x   + (size_t)n * DD + 4 * q);
        const int k = idx[n];
        const float4 ca = *(const float4*)(ccb + (size_t)k * DD + 4 * q);
        const float4 co = *(const float4*)(cnb + (size_t)k * DD + 4 * q);
        sx.x += xv.x; sx.y += xv.y; sx.z += xv.z; sx.w += xv.w;
        sca.x += ca.x; sca.y += ca.y; sca.z += ca.z; sca.w += ca.w;
        sco.x += co.x; sco.y += co.y; sco.z += co.z; sco.w += co.w;
    }
    if (rid > 0) { s_red[rid-1][0][q] = sx; s_red[rid-1][1][q] = sca; s_red[rid-1][2][q] = sco; }
    __syncthreads();
    if (rid == 0) {
        #pragma unroll
        for (int p = 0; p < 7; ++p) {
            float4 a = s_red[p][0][q], b = s_red[p][1][q], c = s_red[p][2][q];
            sx.x += a.x; sx.y += a.y; sx.z += a.z; sx.w += a.w;
            sca.x += b.x; sca.y += b.y; sca.z += b.z; sca.w += b.w;
            sco.x += c.x; sco.y += c.y; sco.z += c.z; sco.w += c.w;
        }
        float cnt = (float)(end - start);
        float inv = 1.f / fmaxf(cnt, 1.f);
        float4 px, pca, pco;
        px.x = sx.x*inv; px.y = sx.y*inv; px.z = sx.z*inv; px.w = sx.w*inv;
        pca.x = px.x + sca.x*inv; pca.y = px.y + sca.y*inv;
        pca.z = px.z + sca.z*inv; pca.w = px.w + sca.w*inv;
        pco.x = sco.x*inv; pco.y = sco.y*inv; pco.z = sco.z*inv; pco.w = sco.w*inv;
        *(float4*)(out + PX_OFF + (size_t)g * DD + 4 * q) = px;
        *(float4*)(out + PC_OFF + (size_t)g * DD + 4 * q) = pca;
        s_pool4[0][q] = pca; s_pool4[1][q] = pco; s_pool4[2][q] = px;
    }
    __syncthreads();
    if (tid < 3 * TT) {
        int vec = tid / TT, t = tid % TT;
        const float* sp = (const float*)&s_pool4[vec][0];
        float a = fcb[t];
        #pragma unroll 8
        for (int j = 0; j < DD; ++j) a = fmaf(sp[j], fcw[t * DD + j], a);
        out[(size_t)vec * GT + (size_t)g * TT + t] = a;
    }
}

extern "C" void kernel_launch(void* const* d_in, const int* in_sizes, int n_in,
                              void* d_out, int out_size, void* d_ws, size_t ws_size,
                              hipStream_t stream) {
    const float* x    = (const float*)d_in[0];
    const void*  batch= d_in[1];
    const float* cb   = (const float*)d_in[2];
    const float* ccb  = (const float*)d_in[3];
    const float* cnb  = (const float*)d_in[4];
    const float* fcw  = (const float*)d_in[5];
    const float* fcb  = (const float*)d_in[6];
    float* out = (float*)d_out;

    float* c2  = (float*)d_ws;
    int*   idx = (int*)((char*)d_ws + 4096);
    unsigned short* bpack = (unsigned short*)(out + PC_OFF);       // 256 KB borrow
    int* flag_cnt  = (int*)(out + PC_OFF + 65536);
    int* flag_list = (int*)(out + PC_OFF + 65537);

    prep_c2_kernel   <<<128,  256, 0, stream>>>(ccb, c2, flag_cnt);
    prep_bpack_kernel<<<64,   256, 0, stream>>>(ccb, bpack);
    argmin_mfma_kernel<<<2048, 256, 0, stream>>>(x, bpack, c2, cb, idx, out + Z_OFF,
                                                 flag_cnt, flag_list);
    rescore_kernel   <<<128,  256, 0, stream>>>(x, ccb, c2, cb, flag_cnt, flag_list,
                                                idx, out + Z_OFF);
    pool_kernel      <<<GG,   256, 0, stream>>>(x, batch, idx, ccb, cnb, fcw, fcb, out);
}